// Round 9
// baseline (69.289 us; speedup 1.0000x reference)
//
#include <hip/hip_runtime.h>

// RandWarpAug: B=512, C=12, T=4096, DS=4, STEPS=7, KS=51
// in[0] = source   [512,12,4096] f32
// in[1] = flow_mag [1]           f32
// in[2] = noise    [512,1,4096]  f32
// in[3] = smooth_kernel [51]     f32
// out   = [512,12,4096] f32

#define BB 512
#define CC 12
#define TT 4096
#define TD 1024
#define KS 51
#define NT 1024
#define NJ 17
#define J0 (-8)
#define T_LO 32
#define T_HI 4063

typedef float f32x4 __attribute__((ext_vector_type(4)));
typedef float f32x2 __attribute__((ext_vector_type(2), aligned(4)));

struct WarpW { int y0c, y1c; float w0, w1; };
struct WarpG { int addr; float a, b; };   // out = a*src[addr] + b*src[addr+1]

// Faithful replication of reference warp_1d coordinate math for one sample.
template <int TLEN>
__device__ __forceinline__ WarpW warp_weights(int t, float flow) {
    const float tm1 = (float)(TLEN - 1);
    float nl = (float)t + flow;                 // new_locs
    float v  = 2.0f * (nl / tm1 - 0.5f);        // normalized
    float ix = (v + 1.0f) * 0.5f;               // W=2 -> (W-1)=1
    float iy = ix * tm1;
    float x0 = floorf(ix);
    float fx = ix - x0;
    int   x0i = (int)x0;
    float m0 = (x0i >= 0 && x0i <= 1) ? 1.0f : 0.0f;
    float m1 = (x0i + 1 >= 0 && x0i + 1 <= 1) ? 1.0f : 0.0f;
    float xw = (1.0f - fx) * m0 + fx * m1;
    float y0 = floorf(iy);
    float fy = iy - y0;
    int   y0i = (int)y0;
    int   y1i = y0i + 1;
    float vy0 = (y0i >= 0 && y0i < TLEN) ? 1.0f : 0.0f;
    float vy1 = (y1i >= 0 && y1i < TLEN) ? 1.0f : 0.0f;
    WarpW r;
    r.y0c = min(max(y0i, 0), TLEN - 1);
    r.y1c = min(max(y1i, 0), TLEN - 1);
    r.w0 = xw * (1.0f - fy) * vy0;
    r.w1 = xw * fy * vy1;
    return r;
}

// Packed gather form: one base address + two fused tap weights.
// Folding the {0,1} offset selects into the weights is exact: the grouping
// only differs from the reference when the corresponding weight is 0.
template <int TLEN>
__device__ __forceinline__ WarpG warp_gather(int t, float flow) {
    const float tm1 = (float)(TLEN - 1);
    float nl = (float)t + flow;
    float v  = 2.0f * (nl / tm1 - 0.5f);
    float ix = (v + 1.0f) * 0.5f;
    float iy = ix * tm1;
    float x0 = floorf(ix);
    float fx = ix - x0;
    int   x0i = (int)x0;
    float m0 = (x0i >= 0 && x0i <= 1) ? 1.0f : 0.0f;
    float m1 = (x0i + 1 >= 0 && x0i + 1 <= 1) ? 1.0f : 0.0f;
    float xw = (1.0f - fx) * m0 + fx * m1;
    float y0 = floorf(iy);
    float fy = iy - y0;
    int   y0i = (int)y0;
    int   y1i = y0i + 1;
    float vy0 = (y0i >= 0 && y0i < TLEN) ? 1.0f : 0.0f;
    float vy1 = (y1i >= 0 && y1i < TLEN) ? 1.0f : 0.0f;
    int y0c = min(max(y0i, 0), TLEN - 1);
    int y1c = min(max(y1i, 0), TLEN - 1);
    float w0 = xw * (1.0f - fy) * vy0;
    float w1 = xw * fy * vy1;
    WarpG r;
    r.addr = min(max(y0i, 0), TLEN - 2);
    int o0 = y0c - r.addr;        // 0 or 1
    int o1 = y1c - r.addr;        // 0 or 1
    r.a = (o0 ? 0.0f : w0) + (o1 ? 0.0f : w1);
    r.b = (o0 ? w0 : 0.0f) + (o1 ? w1 : 0.0f);
    return r;
}

// Boundary path: conv(upsample(vec)) computed directly (zero-pad + clamp).
__device__ __forceinline__ float conv_direct(const float* __restrict__ vec,
                                             const float* __restrict__ g, int t) {
    float acc = 0.0f;
    for (int k = 0; k < KS; ++k) {
        int s = t + k - 25;
        if (s < 0 || s >= TT) continue;
        float srcp = 0.25f * (float)s - 0.375f;
        srcp = fminf(fmaxf(srcp, 0.0f), (float)(TD - 1));
        float flp = floorf(srcp);
        int i0 = (int)flp;
        int i1 = min(i0 + 1, TD - 1);
        float w = srcp - flp;
        acc += g[k] * 4.0f * ((1.0f - w) * vec[i0] + w * vec[i1]);
    }
    return acc;
}

extern "C" __global__ void __launch_bounds__(NT, 8)
rand_warp_aug_kernel(const float* __restrict__ source,
                     const float* __restrict__ flow_mag,
                     const float* __restrict__ noise,
                     const float* __restrict__ gk,
                     float* __restrict__ out) {
    __shared__ float vecA[TD];
    __shared__ float vecB[TD];
    __shared__ float g[KS];
    __shared__ float wtab[NJ][4];   // [j][p], p = t%4 fastest

    const int b   = blockIdx.x;
    const int tid = threadIdx.x;
    const float fm = flow_mag[0];

    // ---- phase 1: flow_field = fm*noise; downsample x4; *0.25 * 1/128 ----
    const f32x4* nrow4 = (const f32x4*)(noise + (size_t)b * TT);
    {
        f32x4 nv = nrow4[tid];
        float x1 = fm * nv.y;
        float x2 = fm * nv.z;
        vecA[tid] = (x1 * 0.5f + x2 * 0.5f) * (0.25f * 0.0078125f);
    }
    if (tid < KS) g[tid] = gk[tid];
    __syncthreads();

    // ---- build fused conv51 ∘ upsample4 stencil table (interior form) ----
    if (tid < 4 * NJ) {
        int p = tid / NJ;
        int j = tid % NJ + J0;
        float acc = 0.0f;
        for (int k = 0; k < KS; ++k) {
            int q = p + k - 25;
            int d = (q >= 0) ? (q >> 2) : -((-q + 3) >> 2);  // floor(q/4)
            int r = q - 4 * d;
            float c = 0.0f;
            if (r == 0)      { if (j == d - 1) c = 0.375f; else if (j == d) c = 0.625f; }
            else if (r == 1) { if (j == d - 1) c = 0.125f; else if (j == d) c = 0.875f; }
            else if (r == 2) { if (j == d)     c = 0.875f; else if (j == d + 1) c = 0.125f; }
            else             { if (j == d)     c = 0.625f; else if (j == d + 1) c = 0.375f; }
            acc += g[k] * c;
        }
        wtab[tid % NJ][p] = 4.0f * acc;
    }
    // (visible after the first VecInt barrier below)

    // ---- phase 2: VecInt scaling-and-squaring, 7 steps, Tlen=1024 ----
    float* cur = vecA;
    float* nxt = vecB;
#pragma unroll 1
    for (int s = 0; s < 7; ++s) {
        {
            float fl = cur[tid];
            WarpW w = warp_weights<TD>(tid, fl);
            nxt[tid] = fl + (w.w0 * cur[w.y0c] + w.w1 * cur[w.y1c]);
        }
        __syncthreads();
        float* tmp = cur; cur = nxt; nxt = tmp;
    }
    // final vec is in `cur`

    // ---- phase 3: fused upsample+conv via 17-tap coarse stencil ----
    const int p  = tid & 3;
    const int Tb = tid >> 2;
    float pf[4];
    {
        float a0 = 0.0f, a1 = 0.0f, a2 = 0.0f, a3 = 0.0f;
#pragma unroll
        for (int j = 0; j < NJ; ++j) {
            float wreg = wtab[j][p];
            int base = Tb + j + J0;
            a0 += wreg * cur[base];
            a1 += wreg * cur[base + 256];
            a2 += wreg * cur[base + 512];
            a3 += wreg * cur[base + 768];
        }
        pf[0] = a0; pf[1] = a1; pf[2] = a2; pf[3] = a3;
    }
    if (tid < T_LO)                  pf[0] = conv_direct(cur, g, tid);
    if (tid >= NT - (TT - 1 - T_HI)) pf[3] = conv_direct(cur, g, tid + 3 * NT);

    // ---- phase 4: warp of source; batch all 12 channel loads per t-group
    //      so 12 global_load_dwordx2 are in flight before first use (MLP) ----
    const float* sbase = source + (size_t)b * CC * TT;
    float*       obase = out    + (size_t)b * CC * TT;
#pragma unroll
    for (int tt = 0; tt < TT / NT; ++tt) {
        int t = tid + tt * NT;
        WarpG w = warp_gather<TT>(t, pf[tt]);
        f32x2 v[CC];
#pragma unroll
        for (int c = 0; c < CC; ++c)
            v[c] = *(const f32x2*)(sbase + (size_t)c * TT + w.addr);
#pragma unroll
        for (int c = 0; c < CC; ++c)
            obase[(size_t)c * TT + t] = w.a * v[c].x + w.b * v[c].y;
    }
}

extern "C" void kernel_launch(void* const* d_in, const int* in_sizes, int n_in,
                              void* d_out, int out_size, void* d_ws, size_t ws_size,
                              hipStream_t stream) {
    const float* source   = (const float*)d_in[0];
    const float* flow_mag = (const float*)d_in[1];
    const float* noise    = (const float*)d_in[2];
    const float* gk       = (const float*)d_in[3];
    float* out = (float*)d_out;

    rand_warp_aug_kernel<<<BB, NT, 0, stream>>>(source, flow_mag, noise, gk, out);
}

// Round 10
// 55.556 us; speedup vs baseline: 1.2472x; 1.2472x over previous
//
#include <hip/hip_runtime.h>

// RandWarpAug: B=512, C=12, T=4096, DS=4, STEPS=7, KS=51
// in[0] = source   [512,12,4096] f32
// in[1] = flow_mag [1]           f32
// in[2] = noise    [512,1,4096]  f32
// in[3] = smooth_kernel [51]     f32
// out   = [512,12,4096] f32

#define BB 512
#define CC 12
#define TT 4096
#define TD 1024
#define KS 51
#define NT 1024
#define NJ 17
#define J0 (-8)
#define T_LO 32
#define T_HI 4063

typedef float f32x4 __attribute__((ext_vector_type(4)));
typedef float f32x2 __attribute__((ext_vector_type(2), aligned(4)));

struct WarpW { int y0c, y1c; float w0, w1; };
struct WarpG { int addr; float a, b; };   // out = a*src[addr] + b*src[addr+1]

// Faithful replication of reference warp_1d coordinate math for one sample.
template <int TLEN>
__device__ __forceinline__ WarpW warp_weights(int t, float flow) {
    const float tm1 = (float)(TLEN - 1);
    float nl = (float)t + flow;                 // new_locs
    float v  = 2.0f * (nl / tm1 - 0.5f);        // normalized
    float ix = (v + 1.0f) * 0.5f;               // W=2 -> (W-1)=1
    float iy = ix * tm1;
    float x0 = floorf(ix);
    float fx = ix - x0;
    int   x0i = (int)x0;
    float m0 = (x0i >= 0 && x0i <= 1) ? 1.0f : 0.0f;
    float m1 = (x0i + 1 >= 0 && x0i + 1 <= 1) ? 1.0f : 0.0f;
    float xw = (1.0f - fx) * m0 + fx * m1;
    float y0 = floorf(iy);
    float fy = iy - y0;
    int   y0i = (int)y0;
    int   y1i = y0i + 1;
    float vy0 = (y0i >= 0 && y0i < TLEN) ? 1.0f : 0.0f;
    float vy1 = (y1i >= 0 && y1i < TLEN) ? 1.0f : 0.0f;
    WarpW r;
    r.y0c = min(max(y0i, 0), TLEN - 1);
    r.y1c = min(max(y1i, 0), TLEN - 1);
    r.w0 = xw * (1.0f - fy) * vy0;
    r.w1 = xw * fy * vy1;
    return r;
}

// Packed gather form: one base address + two fused tap weights.
// Folding the {0,1} offset selects into the weights is exact: the grouping
// only differs from the reference when the corresponding weight is 0.
template <int TLEN>
__device__ __forceinline__ WarpG warp_gather(int t, float flow) {
    const float tm1 = (float)(TLEN - 1);
    float nl = (float)t + flow;
    float v  = 2.0f * (nl / tm1 - 0.5f);
    float ix = (v + 1.0f) * 0.5f;
    float iy = ix * tm1;
    float x0 = floorf(ix);
    float fx = ix - x0;
    int   x0i = (int)x0;
    float m0 = (x0i >= 0 && x0i <= 1) ? 1.0f : 0.0f;
    float m1 = (x0i + 1 >= 0 && x0i + 1 <= 1) ? 1.0f : 0.0f;
    float xw = (1.0f - fx) * m0 + fx * m1;
    float y0 = floorf(iy);
    float fy = iy - y0;
    int   y0i = (int)y0;
    int   y1i = y0i + 1;
    float vy0 = (y0i >= 0 && y0i < TLEN) ? 1.0f : 0.0f;
    float vy1 = (y1i >= 0 && y1i < TLEN) ? 1.0f : 0.0f;
    int y0c = min(max(y0i, 0), TLEN - 1);
    int y1c = min(max(y1i, 0), TLEN - 1);
    float w0 = xw * (1.0f - fy) * vy0;
    float w1 = xw * fy * vy1;
    WarpG r;
    r.addr = min(max(y0i, 0), TLEN - 2);
    int o0 = y0c - r.addr;        // 0 or 1
    int o1 = y1c - r.addr;        // 0 or 1
    r.a = (o0 ? 0.0f : w0) + (o1 ? 0.0f : w1);
    r.b = (o0 ? w0 : 0.0f) + (o1 ? w1 : 0.0f);
    return r;
}

// Boundary path: conv(upsample(vec)) computed directly (zero-pad + clamp).
__device__ __forceinline__ float conv_direct(const float* __restrict__ vec,
                                             const float* __restrict__ g, int t) {
    float acc = 0.0f;
    for (int k = 0; k < KS; ++k) {
        int s = t + k - 25;
        if (s < 0 || s >= TT) continue;
        float srcp = 0.25f * (float)s - 0.375f;
        srcp = fminf(fmaxf(srcp, 0.0f), (float)(TD - 1));
        float flp = floorf(srcp);
        int i0 = (int)flp;
        int i1 = min(i0 + 1, TD - 1);
        float w = srcp - flp;
        acc += g[k] * 4.0f * ((1.0f - w) * vec[i0] + w * vec[i1]);
    }
    return acc;
}

extern "C" __global__ void __launch_bounds__(NT)
rand_warp_aug_kernel(const float* __restrict__ source,
                     const float* __restrict__ flow_mag,
                     const float* __restrict__ noise,
                     const float* __restrict__ gk,
                     float* __restrict__ out) {
    __shared__ float vecA[TD];
    __shared__ float vecB[TD];
    __shared__ float g[KS];
    __shared__ float wtab[NJ][4];   // [j][p], p = t%4 fastest

    const int b   = blockIdx.x;
    const int tid = threadIdx.x;
    const float fm = flow_mag[0];

    // ---- phase 1: flow_field = fm*noise; downsample x4; *0.25 * 1/128 ----
    const f32x4* nrow4 = (const f32x4*)(noise + (size_t)b * TT);
    {
        f32x4 nv = nrow4[tid];
        float x1 = fm * nv.y;
        float x2 = fm * nv.z;
        vecA[tid] = (x1 * 0.5f + x2 * 0.5f) * (0.25f * 0.0078125f);
    }
    if (tid < KS) g[tid] = gk[tid];
    __syncthreads();

    // ---- build fused conv51 ∘ upsample4 stencil table (interior form) ----
    if (tid < 4 * NJ) {
        int p = tid / NJ;
        int j = tid % NJ + J0;
        float acc = 0.0f;
        for (int k = 0; k < KS; ++k) {
            int q = p + k - 25;
            int d = (q >= 0) ? (q >> 2) : -((-q + 3) >> 2);  // floor(q/4)
            int r = q - 4 * d;
            float c = 0.0f;
            if (r == 0)      { if (j == d - 1) c = 0.375f; else if (j == d) c = 0.625f; }
            else if (r == 1) { if (j == d - 1) c = 0.125f; else if (j == d) c = 0.875f; }
            else if (r == 2) { if (j == d)     c = 0.875f; else if (j == d + 1) c = 0.125f; }
            else             { if (j == d)     c = 0.625f; else if (j == d + 1) c = 0.375f; }
            acc += g[k] * c;
        }
        wtab[tid % NJ][p] = 4.0f * acc;
    }
    // (visible after the first VecInt barrier below)

    // ---- phase 2: VecInt scaling-and-squaring, 7 steps, Tlen=1024 ----
    float* cur = vecA;
    float* nxt = vecB;
#pragma unroll 1
    for (int s = 0; s < 7; ++s) {
        {
            float fl = cur[tid];
            WarpW w = warp_weights<TD>(tid, fl);
            nxt[tid] = fl + (w.w0 * cur[w.y0c] + w.w1 * cur[w.y1c]);
        }
        __syncthreads();
        float* tmp = cur; cur = nxt; nxt = tmp;
    }
    // final vec is in `cur`

    // ---- phase 3: fused upsample+conv via 17-tap coarse stencil ----
    const int p  = tid & 3;
    const int Tb = tid >> 2;
    float pf[4];
    {
        float a0 = 0.0f, a1 = 0.0f, a2 = 0.0f, a3 = 0.0f;
#pragma unroll
        for (int j = 0; j < NJ; ++j) {
            float wreg = wtab[j][p];
            int base = Tb + j + J0;
            a0 += wreg * cur[base];
            a1 += wreg * cur[base + 256];
            a2 += wreg * cur[base + 512];
            a3 += wreg * cur[base + 768];
        }
        pf[0] = a0; pf[1] = a1; pf[2] = a2; pf[3] = a3;
    }
    if (tid < T_LO)                  pf[0] = conv_direct(cur, g, tid);
    if (tid >= NT - (TT - 1 - T_HI)) pf[3] = conv_direct(cur, g, tid + 3 * NT);

    // ---- phase 4: warp of source. Named scalars (no array -> no scratch),
    //      sched_barrier(0) between the 12 loads and 12 stores forces all
    //      12 global_load_dwordx2 in flight per wave (MLP=12). ----
    const float* sbase = source + (size_t)b * CC * TT;
    float*       obase = out    + (size_t)b * CC * TT;
#pragma unroll 1
    for (int tt = 0; tt < TT / NT; ++tt) {
        int t = tid + tt * NT;
        WarpG w = warp_gather<TT>(t, pf[tt]);
        int a = w.addr;
#define LD(c) f32x2 v##c = *(const f32x2*)(sbase + (size_t)(c) * TT + a)
        LD(0); LD(1); LD(2); LD(3); LD(4); LD(5);
        LD(6); LD(7); LD(8); LD(9); LD(10); LD(11);
#undef LD
        __builtin_amdgcn_sched_barrier(0);
#define ST(c) obase[(size_t)(c) * TT + t] = w.a * v##c.x + w.b * v##c.y
        ST(0); ST(1); ST(2); ST(3); ST(4); ST(5);
        ST(6); ST(7); ST(8); ST(9); ST(10); ST(11);
#undef ST
    }
}

extern "C" void kernel_launch(void* const* d_in, const int* in_sizes, int n_in,
                              void* d_out, int out_size, void* d_ws, size_t ws_size,
                              hipStream_t stream) {
    const float* source   = (const float*)d_in[0];
    const float* flow_mag = (const float*)d_in[1];
    const float* noise    = (const float*)d_in[2];
    const float* gk       = (const float*)d_in[3];
    float* out = (float*)d_out;

    rand_warp_aug_kernel<<<BB, NT, 0, stream>>>(source, flow_mag, noise, gk, out);
}